// Round 1
// baseline (365.703 us; speedup 1.0000x reference)
//
#include <hip/hip_runtime.h>
#include <hip/hip_bf16.h>

#define BATCH 8
#define LSEQ 2048
#define DDIM 512

using f32x4 = __attribute__((ext_vector_type(4))) float;
using s16x8 = __attribute__((ext_vector_type(8))) short;

static __device__ __forceinline__ unsigned short f2b(float f) {
  __hip_bfloat16 h = __float2bfloat16(f);
  return __builtin_bit_cast(unsigned short, h);
}
static __device__ __forceinline__ float b2f(unsigned short u) {
  unsigned int v = ((unsigned int)u) << 16;
  return __builtin_bit_cast(float, v);
}

// async global->LDS, 16B per lane. LDS dest = wave-uniform base + lane*16.
static __device__ __forceinline__ void gld16(const unsigned short* g, unsigned short* l) {
  __builtin_amdgcn_global_load_lds(
      (__attribute__((address_space(1))) void*)(g),
      (__attribute__((address_space(3))) void*)(l), 16, 0, 0);
}

// 128x128-tile bf16 MFMA K-loop, async staging, row stride 32 (unpadded, required
// by global_load_lds contiguity). 256 threads = 4 waves, 64x64/wave.
__device__ __forceinline__ void mfma_kloop(
    const unsigned short* __restrict__ A, const unsigned short* __restrict__ Bt,
    int K, int lda, int ldb, unsigned short* sA, unsigned short* sB,
    int tid, f32x4 acc[4][4]) {
  const int wave = tid >> 6, lane = tid & 63;
  const int wm = (wave >> 1) * 64, wn = (wave & 1) * 64;
  const int lr = lane & 15, lq = lane >> 4;
  const int srow = tid >> 2;       // 0..63
  const int sk = (tid & 3) * 8;    // 0,8,16,24
  unsigned short* dA0 = sA + wave * 512;          // + implicit lane*8
  unsigned short* dA1 = sA + 2048 + wave * 512;
  unsigned short* dB0 = sB + wave * 512;
  unsigned short* dB1 = sB + 2048 + wave * 512;
  const unsigned short* pa0 = A + (size_t)srow * lda + sk;
  const unsigned short* pa1 = A + (size_t)(srow + 64) * lda + sk;
  const unsigned short* pb0 = Bt + (size_t)srow * ldb + sk;
  const unsigned short* pb1 = Bt + (size_t)(srow + 64) * ldb + sk;
  for (int k0 = 0; k0 < K; k0 += 32) {
    gld16(pa0 + k0, dA0);
    gld16(pa1 + k0, dA1);
    gld16(pb0 + k0, dB0);
    gld16(pb1 + k0, dB1);
    __syncthreads();
    s16x8 af[4], bf[4];
#pragma unroll
    for (int r = 0; r < 4; ++r)
      af[r] = *(const s16x8*)(sA + (wm + r * 16 + lr) * 32 + lq * 8);
#pragma unroll
    for (int c = 0; c < 4; ++c)
      bf[c] = *(const s16x8*)(sB + (wn + c * 16 + lr) * 32 + lq * 8);
#pragma unroll
    for (int r = 0; r < 4; ++r)
#pragma unroll
      for (int c = 0; c < 4; ++c)
        acc[r][c] = __builtin_amdgcn_mfma_f32_16x16x32_bf16(af[r], bf[c], acc[r][c], 0, 0, 0);
    __syncthreads();
  }
}

// Fused f32->bf16 convert + masked partial sum. z selects input a/b.
__global__ __launch_bounds__(256) void k_prep(const float* __restrict__ in_a,
                                              const float* __restrict__ in_b,
                                              const int* __restrict__ ma,
                                              const int* __restrict__ mb,
                                              unsigned short* __restrict__ oa,
                                              unsigned short* __restrict__ ob,
                                              float* __restrict__ Pa,
                                              float* __restrict__ Pb) {
  int z = blockIdx.z;
  const float* in = z ? in_b : in_a;
  const int* mask = z ? mb : ma;
  unsigned short* o16 = z ? ob : oa;
  float* partial = z ? Pb : Pa;
  int b = blockIdx.y;
  int l0 = blockIdx.x * 32;
  __shared__ int sm[32];
  if (threadIdx.x < 32) sm[threadIdx.x] = mask[b * LSEQ + l0 + threadIdx.x];
  __syncthreads();
  int d = threadIdx.x * 2;
  const float* base = in + ((size_t)b * LSEQ + l0) * DDIM + d;
  unsigned short* obase = o16 + ((size_t)b * LSEQ + l0) * DDIM + d;
  float ax = 0.f, ay = 0.f;
#pragma unroll 4
  for (int r = 0; r < 32; ++r) {
    float2 v = *(const float2*)(base + (size_t)r * DDIM);
    ushort2 u; u.x = f2b(v.x); u.y = f2b(v.y);
    *(ushort2*)(obase + (size_t)r * DDIM) = u;
    if (sm[r] == 0) { ax += v.x; ay += v.y; }
  }
  float2 o; o.x = ax; o.y = ay;
  *(float2*)(partial + ((size_t)(b * 64 + blockIdx.x)) * DDIM + d) = o;
}

// Stage 2 for both inputs: C[b,d] = (1/L)*sum partials. grid 16.
__global__ __launch_bounds__(256) void k_p2(const float* __restrict__ Pa,
                                            const float* __restrict__ Pb,
                                            float* __restrict__ Ca,
                                            float* __restrict__ Cb) {
  int g = blockIdx.x;
  const float* src = (g < 8) ? Pa : Pb;
  float* dst = (g < 8) ? Ca : Cb;
  int b = g & 7;
  int d = threadIdx.x * 2;
  float ax = 0.f, ay = 0.f;
  for (int c = 0; c < 64; ++c) {
    float2 v = *(const float2*)(src + ((size_t)(b * 64 + c)) * DDIM + d);
    ax += v.x; ay += v.y;
  }
  dst[b * DDIM + d] = ax * (1.0f / LSEQ);
  dst[b * DDIM + d + 1] = ay * (1.0f / LSEQ);
}

// Both weights [D,H] f32 -> [H,D] bf16. grid 2048 covers 2x512x512.
__global__ __launch_bounds__(256) void k_transposeW(const float* __restrict__ Wa,
                                                    const float* __restrict__ Wb,
                                                    unsigned short* __restrict__ WaT,
                                                    unsigned short* __restrict__ WbT) {
  int gidx = blockIdx.x * 256 + threadIdx.x;
  const float* W = (gidx < 512 * 512) ? Wa : Wb;
  unsigned short* WT = (gidx < 512 * 512) ? WaT : WbT;
  int idx = gidx & (512 * 512 - 1);
  int h = idx >> 9, d = idx & 511;
  WT[idx] = f2b(W[d * DDIM + h]);
}

// mapped = A(bf16) @ W^T(bf16) + bias -> bf16. 1-D grid 1024, XCD-swizzled.
__global__ __launch_bounds__(256) void k_gemm_bias(const unsigned short* __restrict__ a16,
                                                   const unsigned short* __restrict__ b16,
                                                   const unsigned short* __restrict__ WaT,
                                                   const unsigned short* __restrict__ WbT,
                                                   const float* __restrict__ ba,
                                                   const float* __restrict__ bb,
                                                   unsigned short* __restrict__ mapa,
                                                   unsigned short* __restrict__ mapb) {
  int id = blockIdx.x;
  int g = id >> 5, rem = id & 31;
  int bn = (rem >> 3) * 128;
  int f = g * 8 + (rem & 7);   // 0..255
  int bm = (f & 127) * 128;
  int z = f >> 7;
  const unsigned short* A = z ? b16 : a16;
  const unsigned short* Bt = z ? WbT : WaT;
  const float* bias = z ? bb : ba;
  unsigned short* Cout = z ? mapb : mapa;
  __shared__ __align__(16) unsigned short sA[128 * 32], sB[128 * 32];
  f32x4 acc[4][4];
  f32x4 zero = {0.f, 0.f, 0.f, 0.f};
#pragma unroll
  for (int r = 0; r < 4; ++r)
#pragma unroll
    for (int c = 0; c < 4; ++c) acc[r][c] = zero;
  mfma_kloop(A + (size_t)bm * DDIM, Bt + (size_t)bn * DDIM, DDIM, DDIM, DDIM,
             sA, sB, threadIdx.x, acc);
  int wave = threadIdx.x >> 6, lane = threadIdx.x & 63;
  int wm = (wave >> 1) * 64, wn = (wave & 1) * 64, lr = lane & 15, lq = lane >> 4;
#pragma unroll
  for (int r = 0; r < 4; ++r)
#pragma unroll
    for (int c = 0; c < 4; ++c)
#pragma unroll
      for (int rr = 0; rr < 4; ++rr) {
        int row = bm + wm + r * 16 + lq * 4 + rr;
        int col = bn + wn + c * 16 + lr;
        Cout[(size_t)row * DDIM + col] = f2b(acc[r][c][rr] + bias[col]);
      }
}

// E = mask ? exp(scale*mapa.mapb^T) : 0, stored from C-layout (bf16);
// fused row/col sums via shfl butterflies + global atomics.
// 1-D grid 2048, XCD-swizzled: 4x4 (bi,bj) super-tiles colocate on one XCD.
__global__ __launch_bounds__(256) void k_scores(const unsigned short* __restrict__ mapa,
                                                const unsigned short* __restrict__ mapb,
                                                const int* __restrict__ mask_a,
                                                const int* __restrict__ mask_b,
                                                unsigned short* __restrict__ E,
                                                float* __restrict__ Zrow,
                                                float* __restrict__ Zcol) {
  int id = blockIdx.x;
  int low = id & 7, rest = id >> 3;
  int sub = rest & 15, Ghi = rest >> 4;
  int G = Ghi * 8 + low;         // 0..127
  int b = G >> 4, super = G & 15;
  int bi = (((super >> 2) << 2) + (sub >> 2)) * 128;
  int bj = (((super & 3) << 2) + (sub & 3)) * 128;
  __shared__ __align__(16) unsigned short sA[128 * 32], sB[128 * 32];
  __shared__ int sMa[128], sMb[128];
  int tid = threadIdx.x;
  if (tid < 128)
    sMa[tid] = mask_a[b * LSEQ + bi + tid];
  else
    sMb[tid - 128] = mask_b[b * LSEQ + bj + tid - 128];
  f32x4 acc[4][4];
  f32x4 zero = {0.f, 0.f, 0.f, 0.f};
#pragma unroll
  for (int r = 0; r < 4; ++r)
#pragma unroll
    for (int c = 0; c < 4; ++c) acc[r][c] = zero;
  mfma_kloop(mapa + ((size_t)b * LSEQ + bi) * DDIM, mapb + ((size_t)b * LSEQ + bj) * DDIM,
             DDIM, DDIM, DDIM, sA, sB, tid, acc);
  const float scale = 0.044194173824159216f;  // 1/sqrt(512)
  int wave = tid >> 6, lane = tid & 63;
  int wm = (wave >> 1) * 64, wn = (wave & 1) * 64, lr = lane & 15, lq = lane >> 4;
  unsigned short* Eb = E + (size_t)b * LSEQ * LSEQ + (size_t)bi * LSEQ + bj;
  float colp[4] = {0.f, 0.f, 0.f, 0.f};
  float rowp[4][4];
#pragma unroll
  for (int r = 0; r < 4; ++r) {
#pragma unroll
    for (int rr = 0; rr < 4; ++rr) rowp[r][rr] = 0.f;
#pragma unroll
    for (int c = 0; c < 4; ++c) {
      int jl = wn + c * 16 + lr;
      int mb_ = sMb[jl];
#pragma unroll
      for (int rr = 0; rr < 4; ++rr) {
        int il = wm + r * 16 + lq * 4 + rr;
        float e = (sMa[il] && mb_) ? __expf(acc[r][c][rr] * scale) : 0.f;
        rowp[r][rr] += e;
        colp[c] += e;
        Eb[(size_t)il * LSEQ + jl] = f2b(e);
      }
    }
  }
#pragma unroll
  for (int r = 0; r < 4; ++r)
#pragma unroll
    for (int rr = 0; rr < 4; ++rr) {
      float v = rowp[r][rr];
      v += __shfl_xor(v, 1);
      v += __shfl_xor(v, 2);
      v += __shfl_xor(v, 4);
      v += __shfl_xor(v, 8);
      if (lr == 0) {
        int il = wm + r * 16 + lq * 4 + rr;
        atomicAdd(&Zrow[b * LSEQ + bi + il], v);
      }
    }
#pragma unroll
  for (int c = 0; c < 4; ++c) {
    float v = colp[c];
    v += __shfl_xor(v, 16);
    v += __shfl_xor(v, 32);
    if (lq == 0) atomicAdd(&Zcol[b * LSEQ + bj + wn + c * 16 + lr], v);
  }
}

// out[b,d,i] = (Z[b,i]>0 ? 1/Z[b,i] : 0) * in16[b,i,d], transposed store.
__global__ __launch_bounds__(256) void k_scaleT(const unsigned short* __restrict__ a16,
                                                const unsigned short* __restrict__ b16,
                                                const float* __restrict__ Zrow,
                                                const float* __restrict__ Zcol,
                                                unsigned short* __restrict__ atS,
                                                unsigned short* __restrict__ btS) {
  int zz = blockIdx.z;
  int b = zz & 7, sel = zz >> 3;
  const unsigned short* in = sel ? b16 : a16;
  const float* Z = sel ? Zcol : Zrow;
  unsigned short* out = sel ? btS : atS;
  int i0 = blockIdx.y * 64, d0 = blockIdx.x * 64;
  __shared__ unsigned short lt[64 * 65];
  __shared__ float zinv[64];
  if (threadIdx.x < 64) {
    float z = Z[b * LSEQ + i0 + threadIdx.x];
    zinv[threadIdx.x] = (z > 0.f) ? 1.f / z : 0.f;
  }
  __syncthreads();
  const unsigned short* ib = in + ((size_t)b * LSEQ + i0) * DDIM + d0;
#pragma unroll
  for (int p = 0; p < 16; ++p) {
    int idx = p * 256 + threadIdx.x;
    int dl = idx & 63, il = idx >> 6;
    lt[dl * 65 + il] = f2b(b2f(ib[(size_t)il * DDIM + dl]) * zinv[il]);
  }
  __syncthreads();
  unsigned short* ob = out + ((size_t)b * DDIM + d0) * LSEQ + i0;
#pragma unroll
  for (int p = 0; p < 16; ++p) {
    int idx = p * 256 + threadIdx.x;
    int il = idx & 63, dl = idx >> 6;
    ob[(size_t)dl * LSEQ + il] = lt[dl * 65 + il];
  }
}

// Merged output GEMMs: grid 1024 (4 blocks/CU).
//   ids [0,512):   output_a = E @ btS^T + a16 + Cb          (A k-contiguous)
//   ids [512,1024): output_b = E^T @ atS^T + b16 + Ca       (A transposed in-kernel)
// Per-half XCD swizzle: the 4 bn tiles of one (bm,b) share an XCD (E-tile reuse).
__global__ __launch_bounds__(256) void k_gemm_outs(const unsigned short* __restrict__ E,
                                                   const unsigned short* __restrict__ btS,
                                                   const unsigned short* __restrict__ atS,
                                                   const unsigned short* __restrict__ a16,
                                                   const unsigned short* __restrict__ b16,
                                                   const float* __restrict__ Ca,
                                                   const float* __restrict__ Cb,
                                                   float* __restrict__ OutA,
                                                   float* __restrict__ OutB) {
  int id0 = blockIdx.x;
  int modeT = id0 >> 9;          // 0: output_a, 1: output_b
  int id = id0 & 511;
  int g = id >> 5, rem = id & 31;
  int bn = (rem >> 3) * 128;
  int f = g * 8 + (rem & 7);     // 0..127
  int bm = (f & 15) * 128;
  int b = f >> 4;
  const unsigned short* Sop = modeT ? atS : btS;
  const unsigned short* addin = modeT ? b16 : a16;
  const float* Cvec = modeT ? Ca : Cb;
  float* Out = modeT ? OutB : OutA;

  __shared__ __align__(16) unsigned short sA[128 * 32], sB[128 * 32];
  int tid = threadIdx.x;
  const int wave = tid >> 6, lane = tid & 63;
  const int wm = (wave >> 1) * 64, wn = (wave & 1) * 64;
  const int lr = lane & 15, lq = lane >> 4;
  f32x4 acc[4][4];
  f32x4 zero = {0.f, 0.f, 0.f, 0.f};
#pragma unroll
  for (int r = 0; r < 4; ++r)
#pragma unroll
    for (int c = 0; c < 4; ++c) acc[r][c] = zero;

  if (!modeT) {
    mfma_kloop(E + (size_t)b * LSEQ * LSEQ + (size_t)bm * LSEQ,
               Sop + (size_t)b * DDIM * LSEQ + (size_t)bn * LSEQ,
               LSEQ, LSEQ, LSEQ, sA, sB, tid, acc);
  } else {
    const int srow = tid >> 2, sk = (tid & 3) * 8;
    unsigned short* dB0 = sB + wave * 512;
    unsigned short* dB1 = sB + 2048 + wave * 512;
    const unsigned short* Bb = Sop + (size_t)b * DDIM * LSEQ + (size_t)bn * LSEQ;
    const unsigned short* pb0 = Bb + (size_t)srow * LSEQ + sk;
    const unsigned short* pb1 = Bb + (size_t)(srow + 64) * LSEQ + sk;
    const int tc = tid & 15;         // u32 k-pair col
    const int tk = tc * 2;
    const int tm = (tid >> 4) * 8;   // m-chunk (j-cols of E)
    const int gq = tc >> 2, wq = tc & 3;
    const unsigned short* pe = E + (size_t)b * LSEQ * LSEQ + (size_t)tk * LSEQ + bm + tm;
    for (int k0 = 0; k0 < LSEQ; k0 += 32) {
      gld16(pb0 + k0, dB0);
      gld16(pb1 + k0, dB1);
      uint4 e0 = *(const uint4*)(pe + (size_t)k0 * LSEQ);
      uint4 e1 = *(const uint4*)(pe + (size_t)k0 * LSEQ + LSEQ);
      unsigned short t0[8], t1[8];
      *(uint4*)t0 = e0; *(uint4*)t1 = e1;
#pragma unroll
      for (int j = 0; j < 8; ++j) {
        int row = tm + j;
        int sw = gq ^ ((row >> 3) & 3);
        unsigned int v = (unsigned int)t0[j] | ((unsigned int)t1[j] << 16);
        *(unsigned int*)(sA + row * 32 + sw * 8 + wq * 2) = v;
      }
      __syncthreads();
      s16x8 af[4], bf[4];
#pragma unroll
      for (int r = 0; r < 4; ++r) {
        int R = wm + r * 16 + lr;
        af[r] = *(const s16x8*)(sA + R * 32 + ((lq ^ ((R >> 3) & 3)) * 8));
      }
#pragma unroll
      for (int c = 0; c < 4; ++c)
        bf[c] = *(const s16x8*)(sB + (wn + c * 16 + lr) * 32 + lq * 8);
#pragma unroll
      for (int r = 0; r < 4; ++r)
#pragma unroll
        for (int c = 0; c < 4; ++c)
          acc[r][c] = __builtin_amdgcn_mfma_f32_16x16x32_bf16(af[r], bf[c], acc[r][c], 0, 0, 0);
      __syncthreads();
    }
  }

#pragma unroll
  for (int r = 0; r < 4; ++r)
#pragma unroll
    for (int c = 0; c < 4; ++c)
#pragma unroll
      for (int rr = 0; rr < 4; ++rr) {
        int row = bm + wm + r * 16 + lq * 4 + rr;
        int col = bn + wn + c * 16 + lr;
        size_t o = ((size_t)b * LSEQ + row) * DDIM + col;
        Out[o] = acc[r][c][rr] + b2f(addin[o]) + Cvec[b * DDIM + col];
      }
}

extern "C" void kernel_launch(void* const* d_in, const int* in_sizes, int n_in,
                              void* d_out, int out_size, void* d_ws, size_t ws_size,
                              hipStream_t stream) {
  (void)in_sizes; (void)n_in; (void)out_size; (void)ws_size;
  const float* in_a = (const float*)d_in[0];
  const float* in_b = (const float*)d_in[1];
  const int* ma = (const int*)d_in[2];
  const int* mb = (const int*)d_in[3];
  const float* Wa = (const float*)d_in[4];
  const float* ba = (const float*)d_in[5];
  const float* Wb = (const float*)d_in[6];
  const float* bb = (const float*)d_in[7];
  float* out = (float*)d_out;

  char* ws = (char*)d_ws;
  const size_t MB = 1ull << 20;
  unsigned short* a16 = (unsigned short*)(ws + 0 * MB);    // 16MB
  unsigned short* b16 = (unsigned short*)(ws + 16 * MB);   // 16MB
  unsigned short* WaT = (unsigned short*)(ws + 32 * MB);   // 0.5MB
  unsigned short* WbT = (unsigned short*)(ws + 32 * MB + 512 * 1024);
  unsigned short* mapa = (unsigned short*)(ws + 33 * MB);  // 16MB
  unsigned short* mapb = (unsigned short*)(ws + 49 * MB);  // 16MB
  unsigned short* E = (unsigned short*)(ws + 65 * MB);     // 64MB
  unsigned short* atS = (unsigned short*)(ws + 129 * MB);  // 16MB
  unsigned short* btS = (unsigned short*)(ws + 145 * MB);  // 16MB
  float* Zrow = (float*)(ws + 161 * MB);                   // 64KB
  float* Zcol = (float*)(ws + 161 * MB + 65536);           // 64KB
  float* Ca = (float*)(ws + 161 * MB + 2 * 65536);         // 16KB
  float* Cb = (float*)(ws + 161 * MB + 2 * 65536 + 16384); // 16KB
  float* Pa = (float*)(ws + 162 * MB);                     // 1MB
  float* Pb = (float*)(ws + 163 * MB);                     // 1MB

  hipMemsetAsync(Zrow, 0, 2 * 65536, stream);  // Zrow + Zcol
  k_prep<<<dim3(64, 8, 2), 256, 0, stream>>>(in_a, in_b, ma, mb, a16, b16, Pa, Pb);
  k_transposeW<<<2048, 256, 0, stream>>>(Wa, Wb, WaT, WbT);
  k_p2<<<16, 256, 0, stream>>>(Pa, Pb, Ca, Cb);
  k_gemm_bias<<<1024, 256, 0, stream>>>(a16, b16, WaT, WbT, ba, bb, mapa, mapb);
  k_scores<<<2048, 256, 0, stream>>>(mapa, mapb, ma, mb, E, Zrow, Zcol);
  k_scaleT<<<dim3(8, 32, 16), 256, 0, stream>>>(a16, b16, Zrow, Zcol, atS, btS);
  k_gemm_outs<<<1024, 256, 0, stream>>>(E, btS, atS, a16, b16, Ca, Cb,
                                        out, out + (size_t)BATCH * LSEQ * DDIM);
}